// Round 3
// baseline (81.786 us; speedup 1.0000x reference)
//
#include <hip/hip_runtime.h>
#include <hip/hip_bf16.h>
#include <stdint.h>

#define DI __device__ __forceinline__

typedef __attribute__((ext_vector_type(8))) short short8;
typedef __attribute__((ext_vector_type(4))) float f32x4;

// ---------- constants (shapes fixed by setup_inputs) ----------
constexpr int CH   = 128;
constexpr int FH   = 120;
constexpr int FW   = 120;
constexpr int NBOX = 512;
constexpr int KDIM = 49 * 128;   // 6272
constexpr int D1   = 512;
constexpr int D2   = 256;
constexpr int SPLITS = 14;
constexpr int KC     = KDIM / SPLITS; // 448 (14 k-steps of 32)

DI float bf2f(uint32_t u16) { union { uint32_t i; float f; } v; v.i = u16 << 16; return v.f; }
DI uint16_t f2bf(float f) {
    __hip_bfloat16 h = __float2bfloat16(f);
    union { __hip_bfloat16 h; uint16_t u; } v; v.h = h; return v.u;
}

// ---------- 1) features [128,120,120] f32 -> ft [120,120,128] bf16 (as u32 pairs) ----------
__global__ __launch_bounds__(256) void k_tfeat(const float* __restrict__ f,
                                               uint32_t* __restrict__ ft) {
    __shared__ float lds[128 * 121];
    const int y = blockIdx.x;
    const int t = threadIdx.x;
    for (int e = t; e < 128 * 120; e += 256) {
        int c = e / 120, x = e - c * 120;
        lds[c * 121 + x] = f[c * (FH * FW) + y * FW + x];
    }
    __syncthreads();
    const int rowbase = y * FW * (CH / 2);
    for (int e = t; e < FW * (CH / 2); e += 256) {
        int x = e >> 6, cp = e & 63;
        float lo = lds[(2 * cp) * 121 + x];
        float hi = lds[(2 * cp + 1) * 121 + x];
        ft[rowbase + e] = (uint32_t)f2bf(lo) | ((uint32_t)f2bf(hi) << 16);
    }
}

// ---------- 2) W1 [6272,512] f32 -> W1rT [512][6272] bf16, row map r'=b*128+c <- r=c*49+b ----------
__global__ __launch_bounds__(256) void k_w1t(const float* __restrict__ W1,
                                             uint16_t* __restrict__ W1rT) {
    __shared__ float lds[32 * 33];
    const int b = blockIdx.x;           // 0..48
    const int c0 = blockIdx.y * 32;     // 0..96
    const int j0 = blockIdx.z * 32;     // 0..480
    const int t = threadIdx.x;
    for (int e = t; e < 1024; e += 256) {
        int ci = e >> 5, jj = e & 31;
        lds[ci * 33 + jj] = W1[((c0 + ci) * 49 + b) * D1 + j0 + jj];
    }
    __syncthreads();
    for (int e = t; e < 1024; e += 256) {
        int jj = e >> 5, ci = e & 31;
        W1rT[(size_t)(j0 + jj) * KDIM + b * 128 + c0 + ci] = f2bf(lds[ci * 33 + jj]);
    }
}

// ---------- 3) W2 [512,256] f32 -> W2T [256][512] bf16 ----------
__global__ __launch_bounds__(256) void k_w2t(const float* __restrict__ W2,
                                             uint16_t* __restrict__ W2T) {
    __shared__ float lds[32 * 33];
    const int k0 = blockIdx.x * 32;     // 0..480
    const int n0 = blockIdx.y * 32;     // 0..224
    const int t = threadIdx.x;
    for (int e = t; e < 1024; e += 256) {
        int ki = e >> 5, nn = e & 31;
        lds[ki * 33 + nn] = W2[(k0 + ki) * D2 + n0 + nn];
    }
    __syncthreads();
    for (int e = t; e < 1024; e += 256) {
        int nn = e >> 5, ki = e & 31;
        W2T[(n0 + nn) * D1 + k0 + ki] = f2bf(lds[ki * 33 + nn]);
    }
}

// ---------- 4) ROI align: one wave per (box,bin); lane = channel pair ----------
// A layout: [box][bin][ch] bf16  => A row (box) has k = bin*128 + ch, matching W1rT.
__global__ __launch_bounds__(256) void k_roi(const uint32_t* __restrict__ ft,
                                             const float* __restrict__ boxes,
                                             uint32_t* __restrict__ A) {
#pragma clang fp contract(off)
    const int wid  = (blockIdx.x << 2) + (threadIdx.x >> 6); // 0..25087
    const int lane = threadIdx.x & 63;
    const int box = wid / 49, bin = wid % 49;
    const int ph = bin / 7, pw = bin % 7;

    const float bx = boxes[box * 4 + 0], by = boxes[box * 4 + 1];
    const float bw = boxes[box * 4 + 2], bh = boxes[box * 4 + 3];
    const float x1 = bx * 120.0f - 0.5f;
    const float y1 = by * 120.0f - 0.5f;
    const float roi_w = bw * 120.0f, roi_h = bh * 120.0f;
    const float bin_w = roi_w / 7.0f, bin_h = roi_h / 7.0f;
    const float gwf = fmaxf(ceilf(roi_w / 7.0f), 1.0f);
    const float ghf = fmaxf(ceilf(roi_h / 7.0f), 1.0f);
    const int gwi = (int)gwf, ghi = (int)ghf;

    const float ybase = y1 + (float)ph * bin_h;
    const float xbase = x1 + (float)pw * bin_w;

    float acc0 = 0.0f, acc1 = 0.0f;
    for (int sy = 0; sy < ghi; ++sy) {
        float yy = ybase + ((float)sy + 0.5f) * bin_h / ghf;
        bool vy = (yy > -1.0f) && (yy < 120.0f);
        float yc = fminf(fmaxf(yy, 0.0f), 119.0f);
        int y0 = (int)floorf(yc);
        int yh = min(y0 + 1, 119);
        float ly = yc - (float)y0, hy = 1.0f - ly;
        const uint32_t* r0 = ft + (size_t)(y0 * FW) * 64;
        const uint32_t* r1 = ft + (size_t)(yh * FW) * 64;
        for (int sx = 0; sx < gwi; ++sx) {
            float xx = xbase + ((float)sx + 0.5f) * bin_w / gwf;
            if (!(vy && (xx > -1.0f) && (xx < 120.0f))) continue;
            float xc = fminf(fmaxf(xx, 0.0f), 119.0f);
            int x0 = (int)floorf(xc);
            int xh = min(x0 + 1, 119);
            float lx = xc - (float)x0, hx = 1.0f - lx;
            float w00 = hy * hx, w01 = hy * lx, w10 = ly * hx, w11 = ly * lx;
            uint32_t u00 = r0[x0 * 64 + lane];
            uint32_t u01 = r0[xh * 64 + lane];
            uint32_t u10 = r1[x0 * 64 + lane];
            uint32_t u11 = r1[xh * 64 + lane];
            acc0 += w00 * bf2f(u00 & 0xffffu) + w01 * bf2f(u01 & 0xffffu)
                  + w10 * bf2f(u10 & 0xffffu) + w11 * bf2f(u11 & 0xffffu);
            acc1 += w00 * bf2f(u00 >> 16) + w01 * bf2f(u01 >> 16)
                  + w10 * bf2f(u10 >> 16) + w11 * bf2f(u11 >> 16);
        }
    }
    const float cnt = ghf * gwf;
    const float v0 = acc0 / cnt, v1 = acc1 / cnt;
    A[(size_t)wid * 64 + lane] = (uint32_t)f2bf(v0) | ((uint32_t)f2bf(v1) << 16);
}

// ---------- 5) GEMM1 split-K: P[s][512][512] += A[512,6272] * W1rT[512,6272]^T ----------
// 128x128 tile, BK=32, 4 waves (2x2), each wave 4x4 frags of 16x16x32 bf16 MFMA.
// LDS chunk (row, c8) stored at c8 ^ ((row>>1)&3) to keep ds_read_b128 2-way (free).
__global__ __launch_bounds__(256) void k_gemm1(const uint16_t* __restrict__ A,
                                               const uint16_t* __restrict__ B,
                                               float* __restrict__ P) {
    __shared__ __align__(16) uint16_t As[128 * 32];
    __shared__ __align__(16) uint16_t Bs[128 * 32];
    const int t = threadIdx.x;
    const int lane = t & 63, w = t >> 6;
    const int wr = w >> 1, wc = w & 1;
    const int m0 = blockIdx.x * 128, n0 = blockIdx.y * 128;
    const int kbase = blockIdx.z * KC;

    f32x4 acc[4][4] = {};
    const int kb = lane >> 4, r16 = lane & 15;

    for (int ks = 0; ks < KC / 32; ++ks) {
        const int kk = kbase + ks * 32;
        __syncthreads();
#pragma unroll
        for (int i = 0; i < 2; ++i) {
            int ch = t + 256 * i;
            int row = ch >> 2, c8 = ch & 3;
            int sw = (row >> 1) & 3;
            const uint16_t* ga = A + (size_t)(m0 + row) * KDIM + kk + c8 * 8;
            *(uint4*)&As[row * 32 + (c8 ^ sw) * 8] = *(const uint4*)ga;
            const uint16_t* gb = B + (size_t)(n0 + row) * KDIM + kk + c8 * 8;
            *(uint4*)&Bs[row * 32 + (c8 ^ sw) * 8] = *(const uint4*)gb;
        }
        __syncthreads();

        short8 af[4], bfr[4];
#pragma unroll
        for (int mi = 0; mi < 4; ++mi) {
            int ar = wr * 64 + mi * 16 + r16;
            af[mi] = *(const short8*)&As[ar * 32 + (kb ^ ((ar >> 1) & 3)) * 8];
        }
#pragma unroll
        for (int ni = 0; ni < 4; ++ni) {
            int br = wc * 64 + ni * 16 + r16;
            bfr[ni] = *(const short8*)&Bs[br * 32 + (kb ^ ((br >> 1) & 3)) * 8];
        }
#pragma unroll
        for (int mi = 0; mi < 4; ++mi)
#pragma unroll
            for (int ni = 0; ni < 4; ++ni)
                acc[mi][ni] = __builtin_amdgcn_mfma_f32_16x16x32_bf16(af[mi], bfr[ni], acc[mi][ni], 0, 0, 0);
    }

    float* outp = P + (size_t)blockIdx.z * (D1 * D1);
#pragma unroll
    for (int mi = 0; mi < 4; ++mi)
#pragma unroll
        for (int ni = 0; ni < 4; ++ni) {
            int row = m0 + wr * 64 + mi * 16 + kb * 4;
            int col = n0 + wc * 64 + ni * 16 + r16;
#pragma unroll
            for (int r = 0; r < 4; ++r)
                outp[(size_t)(row + r) * D1 + col] = acc[mi][ni][r];
        }
}

// ---------- 6) reduce split-K + bias + ReLU -> H bf16 [512][512] ----------
__global__ __launch_bounds__(256) void k_reduce1(const float* __restrict__ P,
                                                 const float* __restrict__ b1,
                                                 uint16_t* __restrict__ Hm) {
    const int e = blockIdx.x * 256 + threadIdx.x; // 262144 total
    float s = 0.0f;
#pragma unroll
    for (int i = 0; i < SPLITS; ++i) s += P[(size_t)i * (D1 * D1) + e];
    s += b1[e & (D1 - 1)];
    s = fmaxf(s, 0.0f);
    Hm[e] = f2bf(s);
}

// ---------- 7) GEMM2: out[512,256] = H[512,512] * W2T[256,512]^T + b2 ----------
// one wave per 16x16 output tile, operands streamed from L2, no LDS.
__global__ __launch_bounds__(256) void k_gemm2(const uint16_t* __restrict__ Hm,
                                               const uint16_t* __restrict__ W2T,
                                               const float* __restrict__ b2,
                                               float* __restrict__ out) {
    const int wid  = blockIdx.x * 4 + (threadIdx.x >> 6); // 0..511
    const int lane = threadIdx.x & 63;
    const int mt = wid >> 4, nt = wid & 15;
    const int m0 = mt * 16, n0 = nt * 16;
    const int g = lane >> 4, i = lane & 15;
    f32x4 acc = {};
#pragma unroll
    for (int kk = 0; kk < D1 / 32; ++kk) {
        short8 a = *(const short8*)&Hm[(m0 + i) * D1 + kk * 32 + g * 8];
        short8 b = *(const short8*)&W2T[(n0 + i) * D1 + kk * 32 + g * 8];
        acc = __builtin_amdgcn_mfma_f32_16x16x32_bf16(a, b, acc, 0, 0, 0);
    }
    const float bias = b2[n0 + i];
#pragma unroll
    for (int r = 0; r < 4; ++r)
        out[(size_t)(m0 + g * 4 + r) * D2 + n0 + i] = acc[r] + bias;
}

extern "C" void kernel_launch(void* const* d_in, const int* in_sizes, int n_in,
                              void* d_out, int out_size, void* d_ws, size_t ws_size,
                              hipStream_t stream) {
    const float* f     = (const float*)d_in[0];
    const float* boxes = (const float*)d_in[1];
    const float* W1    = (const float*)d_in[2];
    const float* b1    = (const float*)d_in[3];
    const float* W2    = (const float*)d_in[4];
    const float* b2    = (const float*)d_in[5];
    float* out = (float*)d_out;

    char* p = (char*)d_ws;
    uint32_t* ft   = (uint32_t*)p; p += (size_t)FH * FW * (CH / 2) * 4;  // 3,686,400
    uint16_t* W1rT = (uint16_t*)p; p += (size_t)D1 * KDIM * 2;           // 6,422,528
    uint16_t* W2T  = (uint16_t*)p; p += (size_t)D2 * D1 * 2;             //   262,144
    uint16_t* Ar   = (uint16_t*)p; p += (size_t)NBOX * KDIM * 2;         // 6,422,528
    float*    Pp   = (float*)p;    p += (size_t)SPLITS * D1 * D1 * 4;    // 14,680,064
    uint16_t* Hm   = (uint16_t*)p; p += (size_t)D1 * D1 * 2;             //   524,288
    // total ~32.0 MB

    k_tfeat<<<FH, 256, 0, stream>>>(f, ft);
    k_w1t<<<dim3(49, 4, 16), 256, 0, stream>>>(W1, W1rT);
    k_w2t<<<dim3(16, 8), 256, 0, stream>>>(W2, W2T);
    k_roi<<<(NBOX * 49) / 4, 256, 0, stream>>>(ft, boxes, (uint32_t*)Ar);
    k_gemm1<<<dim3(4, 4, SPLITS), 256, 0, stream>>>(Ar, W1rT, Pp);
    k_reduce1<<<(D1 * D1) / 256, 256, 0, stream>>>(Pp, b1, Hm);
    k_gemm2<<<(D1 / 16) * (D2 / 16) / 4, 256, 0, stream>>>(Hm, W2T, b2, out);
}